// Round 15
// baseline (589.722 us; speedup 1.0000x reference)
//
#include <hip/hip_runtime.h>
#include <math.h>

typedef _Float16 f16;
typedef _Float16 f16x8 __attribute__((ext_vector_type(8)));
typedef _Float16 f16x4 __attribute__((ext_vector_type(4)));
typedef float f32x4 __attribute__((ext_vector_type(4)));

#define LDSK 40          // 32 + 8 pad for staged feat tiles
#define NTOK 1025
#define CC 768
#define HH 12
#define DD 64
#define MM 256
#define VPAD 1056        // 33*32 padded token count for vT
#define BN_ROWS 32800    // 32*1025

// ---------------- staging loads: 16 f16; f32 converts on the fly ----------------
__device__ __forceinline__ void load_row16(const f16* p, f16x8& a0, f16x8& a1) {
    a0 = *(const f16x8*)p;
    a1 = *(const f16x8*)(p + 8);
}
__device__ __forceinline__ void load_row16(const float* p, f16x8& a0, f16x8& a1) {
    const float4* q = (const float4*)p;
    float4 u0 = q[0], u1 = q[1], u2 = q[2], u3 = q[3];
    a0[0] = (f16)u0.x; a0[1] = (f16)u0.y; a0[2] = (f16)u0.z; a0[3] = (f16)u0.w;
    a0[4] = (f16)u1.x; a0[5] = (f16)u1.y; a0[6] = (f16)u1.z; a0[7] = (f16)u1.w;
    a1[0] = (f16)u2.x; a1[1] = (f16)u2.y; a1[2] = (f16)u2.z; a1[3] = (f16)u2.w;
    a1[4] = (f16)u3.x; a1[5] = (f16)u3.y; a1[6] = (f16)u3.z; a1[7] = (f16)u3.w;
}

// async global->LDS, 16B per lane, LDS dest wave-uniform base + lane*16
__device__ __forceinline__ void gload16(const f16* g, f16* l) {
    __builtin_amdgcn_global_load_lds(
        (const __attribute__((address_space(1))) unsigned int*)g,
        (__attribute__((address_space(3))) unsigned int*)l, 16, 0, 0);
}

// ---------------- small kernels ----------------
__global__ void k_diag(float* out, float v) {
    if (threadIdx.x == 0 && blockIdx.x == 0) out[0] = v;
}

__global__ __launch_bounds__(256) void k_cvt_x(const float* __restrict__ x, f16* __restrict__ xw) {
    size_t i = ((size_t)blockIdx.x * 256 + threadIdx.x) * 4;   // covers 32896*768
    float4 v;
    if (i < (size_t)BN_ROWS * CC) v = *(const float4*)(x + i);
    else v = make_float4(0.f, 0.f, 0.f, 0.f);
    f16x4 o; o[0] = (f16)v.x; o[1] = (f16)v.y; o[2] = (f16)v.z; o[3] = (f16)v.w;
    *(f16x4*)(xw + i) = o;
}

// merged weight conversions: [0,6912) wqkv, [6912,9216) wproj, [9216,9280) pfeat
__global__ __launch_bounds__(256) void k_prep(const float* __restrict__ w_qkv, const float* __restrict__ w_proj,
                                              const float* __restrict__ proj_feat,
                                              f16* __restrict__ wqkv16, f16* __restrict__ wproj16,
                                              f16* __restrict__ pfeat16) {
    int b = blockIdx.x;
    if (b < 6912) {
        long j = (long)b * 256 + threadIdx.x;
        wqkv16[j] = (f16)w_qkv[j];
    } else if (b < 9216) {
        long j = (long)(b - 6912) * 256 + threadIdx.x;
        wproj16[j] = (f16)w_proj[j];
    } else {
        long j = (long)(b - 9216) * 256 + threadIdx.x;
        pfeat16[j] = (f16)(proj_feat[j] * 0.3535533906f);   // fold D^-0.25
    }
}

// merged post-qkv: [0,384) zero v16t pad cols; [384,576) CLS norm_sq
__global__ __launch_bounds__(256) void k_post(f16* __restrict__ v16t,
                                              const f16* __restrict__ q16, const f16* __restrict__ k16,
                                              float* __restrict__ nsqq, float* __restrict__ nsqk) {
    int blk = blockIdx.x;
    if (blk < 384) {
        int bh = blk;
        for (int u = threadIdx.x; u < 64 * 31; u += 256) {
            int d = u / 31, j = u - d * 31;
            v16t[((size_t)bh * DD + d) * VPAD + 1025 + j] = (f16)0.f;
        }
    } else {
        int gw = ((blk - 384) * 256 + threadIdx.x) >> 6;   // 0..767
        int lane = threadIdx.x & 63;
        int which = gw & 1; int bh = gw >> 1;
        const f16* src = (which ? k16 : q16) + (size_t)bh * NTOK * DD;
        float v = (float)src[lane];
        float ss = v * v;
        for (int off = 1; off < 64; off <<= 1) ss += __shfl_xor(ss, off);
        if (lane == 0) (which ? nsqk : nsqq)[(size_t)bh * NTOK] = ss * (1.f / 16.f);
    }
}

// a[h,k] = -2 * sum_d c_row[h,d] * sin(2*pi*k*d/64);  b likewise from c_col
__global__ __launch_bounds__(64) void k_ab(const float* __restrict__ c_row,
                                           const float* __restrict__ c_col,
                                           float* __restrict__ ab) {
    int h = blockIdx.x, k = threadIdx.x;
    float sa = 0.f, sb = 0.f;
    for (int d = 0; d < 64; ++d) {
        float s = sinf((float)((k * d) & 63) * (6.283185307179586f / 64.f));
        sa += c_row[h * 64 + d] * s;
        sb += c_col[h * 64 + d] * s;
    }
    ab[h * 64 + k] = -2.f * sa;
    ab[768 + h * 64 + k] = -2.f * sb;
}

// w[h,p,t] = (1/64) * sum_k cos(theta_k + 2*pi*k*t/64); 4 hp per 256-thread block
__global__ __launch_bounds__(256) void k_wcirc(const float* __restrict__ ab, float* __restrict__ wc) {
    int grp = threadIdx.x >> 6;
    int t = threadIdx.x & 63;
    int hp = blockIdx.x * 4 + grp;                 // grid 3072
    int h = hp >> 10; int p = hp & 1023;
    float pr = (float)(p >> 5), pc = (float)(p & 31);
    __shared__ float th[4][64];
    th[grp][t] = pr * ab[h * 64 + t] + pc * ab[768 + h * 64 + t];
    __syncthreads();
    float s = 0.f;
    #pragma unroll 8
    for (int k = 0; k < 64; ++k) {
        float arg = th[grp][k] + (float)((k * t) & 63) * (6.283185307179586f / 64.f);
        s += __cosf(arg);
    }
    wc[(size_t)hp * 64 + t] = s * (1.f / 64.f);
}

// ---------------- legacy reg-staged 128x128 core (fallback path) ----------------
template <bool GA, typename TA, typename TB>
__device__ __forceinline__ void gemm128_core(const TA* __restrict__ A, const TB* __restrict__ Bm,
                                             int K, int row0, int col0, int Alim,
                                             f32x4 (&acc)[4][4],
                                             f16 (*As)[LDSK], f16 (*Bs)[LDSK]) {
    const int tid = threadIdx.x;
    const int lane = tid & 63;
    const int lr = tid >> 1, lk = (tid & 1) * 16;
    const int frow = lane & 15, fk = (lane >> 4) * 8;
    const int wave = tid >> 6, wr = wave >> 1, wc = wave & 1;
    for (int kt = 0; kt < K; kt += 32) {
        f16x8 a0 = {}, a1 = {}, b0, b1;
        if (!GA || (row0 + lr) < Alim)
            load_row16(A + (size_t)(row0 + lr) * K + kt + lk, a0, a1);
        load_row16(Bm + (size_t)(col0 + lr) * K + kt + lk, b0, b1);
        __syncthreads();
        *(f16x8*)&As[lr][lk] = a0; *(f16x8*)&As[lr][lk + 8] = a1;
        *(f16x8*)&Bs[lr][lk] = b0; *(f16x8*)&Bs[lr][lk + 8] = b1;
        __syncthreads();
        f16x8 af[4], bf[4];
        #pragma unroll
        for (int m = 0; m < 4; ++m) af[m] = *(const f16x8*)&As[wr * 64 + m * 16 + frow][fk];
        #pragma unroll
        for (int n = 0; n < 4; ++n) bf[n] = *(const f16x8*)&Bs[wc * 64 + n * 16 + frow][fk];
        #pragma unroll
        for (int m = 0; m < 4; ++m)
            #pragma unroll
            for (int n = 0; n < 4; ++n)
                acc[m][n] = __builtin_amdgcn_mfma_f32_16x16x32_f16(af[m], bf[n], acc[m][n], 0, 0, 0);
    }
}

// ---------------- 256x256 DMA-staged core: BK=64, T2 swizzle, dbuf + phase stagger ----------------
__device__ __forceinline__ void gemm256_pipe(const f16* __restrict__ A, const f16* __restrict__ Bm,
                                             int row0, int col0, int aclamp, int stag,
                                             f32x4 (&acc)[8][4], f16* As, f16* Bs) {
    const int tid = threadIdx.x;
    const int lane = tid & 63, w = tid >> 6;
    const int frow = lane & 15;
    const int srow = lane >> 3;                       // 8 rows x 128B per wave-issue
    const int schk = ((lane & 7) ^ srow) * 8;         // inverse-swizzled source col (f16)
    const f16* aG[4]; const f16* bG[4];
    f16* aL[4]; f16* bL[4];
    #pragma unroll
    for (int j = 0; j < 4; ++j) {
        int ra = row0 + w * 32 + 8 * j + srow;
        if (ra > aclamp) ra = aclamp;                 // clamped rows are masked in epilogue
        aG[j] = A + (size_t)ra * CC + schk;
        bG[j] = Bm + (size_t)(col0 + w * 32 + 8 * j + srow) * CC + schk;
        aL[j] = As + (w * 32 + 8 * j) * 64;
        bL[j] = Bs + (w * 32 + 8 * j) * 64;
    }
    auto STAGE = [&](int tt) {
        int bo = (tt & 1) * 16384, ko = tt * 64;
        #pragma unroll
        for (int j = 0; j < 4; ++j) {
            gload16(aG[j] + ko, aL[j] + bo);
            gload16(bG[j] + ko, bL[j] + bo);
        }
    };
    STAGE(0);
    // phase stagger: break co-resident block convoy (0/512/1024/1536 cy)
    switch (stag & 3) {
        case 1: __builtin_amdgcn_s_sleep(8);  break;
        case 2: __builtin_amdgcn_s_sleep(16); break;
        case 3: __builtin_amdgcn_s_sleep(24); break;
        default: break;
    }
    const int wr = w >> 2, wcn = w & 3;
    const int fk8 = (lane >> 4) * 8;
    const int cswz = (frow & 7) * 8;
    for (int t = 0; t < 12; ++t) {
        asm volatile("s_waitcnt vmcnt(0)" ::: "memory");   // tile t landed (issued iter t-1)
        __builtin_amdgcn_s_barrier();
        __builtin_amdgcn_sched_barrier(0);                 // nothing crosses the barrier
        if (t < 11) STAGE(t + 1);                          // fly next tile under this compute
        const f16* Ac = As + (t & 1) * 16384;
        const f16* Bc = Bs + (t & 1) * 16384;
        #pragma unroll
        for (int ks = 0; ks < 2; ++ks) {
            const int co = (ks * 32 + fk8) ^ cswz;
            f16x8 af[8], bf[4];
            #pragma unroll
            for (int n = 0; n < 4; ++n)
                bf[n] = *(const f16x8*)&Bc[(wcn * 64 + n * 16 + frow) * 64 + co];
            #pragma unroll
            for (int m = 0; m < 8; ++m)
                af[m] = *(const f16x8*)&Ac[(wr * 128 + m * 16 + frow) * 64 + co];
            #pragma unroll
            for (int n = 0; n < 4; ++n)
                #pragma unroll
                for (int m = 0; m < 8; ++m)
                    acc[m][n] = __builtin_amdgcn_mfma_f32_16x16x32_f16(af[m], bf[n], acc[m][n], 0, 0, 0);
        }
    }
}

// 256^2 qkv: 1-D grid 1161 = 129 x 9, bijective XCD swizzle, col-tile fastest
__global__ __launch_bounds__(512, 2) void k_gemm_qkv_256(const f16* __restrict__ A, const f16* __restrict__ Bm,
                                                         f16* __restrict__ q16, f16* __restrict__ k16,
                                                         f16* __restrict__ v16t) {
    __shared__ __attribute__((aligned(16))) f16 As[2 * 256 * 64];
    __shared__ __attribute__((aligned(16))) f16 Bs[2 * 256 * 64];
    const int q = 145, r = 1;                       // nwg = 1161
    int xg = blockIdx.x & 7, o8 = blockIdx.x >> 3;
    int wg = (xg < r ? xg * (q + 1) : r * (q + 1) + (xg - r) * q) + o8;
    int row0 = (wg / 9) * 256, col0 = (wg % 9) * 256;
    f32x4 acc[8][4] = {};
    gemm256_pipe(A, Bm, row0, col0, 32895, wg & 3, acc, As, Bs);
    // epilogue: per-wave constant (t, h); scatter into q16/k16/v16t
    const int lane = threadIdx.x & 63, w = threadIdx.x >> 6;
    const int wr = w >> 2, wcn = w & 3;
    int cb = col0 + wcn * 64 + (lane & 15);
    int tt = cb / CC;
    int h = (cb - tt * CC) >> 6;
    int d0 = lane & 15;
    int rb = row0 + wr * 128 + 4 * (lane >> 4);
    #pragma unroll
    for (int m = 0; m < 8; ++m)
        #pragma unroll
        for (int i = 0; i < 4; ++i) {
            int rr = rb + m * 16 + i;
            if (rr >= BN_ROWS) continue;
            int b = rr / NTOK, nn = rr - b * NTOK;
            size_t bh = (size_t)b * HH + h;
            if (tt == 0) {
                f16* p = q16 + (bh * NTOK + nn) * DD + d0;
                #pragma unroll
                for (int n = 0; n < 4; ++n) p[n * 16] = (f16)acc[m][n][i];
            } else if (tt == 1) {
                f16* p = k16 + (bh * NTOK + nn) * DD + d0;
                #pragma unroll
                for (int n = 0; n < 4; ++n) p[n * 16] = (f16)acc[m][n][i];
            } else {
                f16* p = v16t + (bh * DD + d0) * VPAD + nn;
                #pragma unroll
                for (int n = 0; n < 4; ++n) p[(size_t)n * 16 * VPAD] = (f16)acc[m][n][i];
            }
        }
}

// 256^2 proj: 1-D grid 387 = 129 x 3, bijective XCD swizzle
__global__ __launch_bounds__(512, 2) void k_gemm_proj_256(const f16* __restrict__ A, const f16* __restrict__ Bm,
                                                          const float* __restrict__ bias, float* __restrict__ out) {
    __shared__ __attribute__((aligned(16))) f16 As[2 * 256 * 64];
    __shared__ __attribute__((aligned(16))) f16 Bs[2 * 256 * 64];
    const int q = 48, r = 3;                        // nwg = 387
    int xg = blockIdx.x & 7, o8 = blockIdx.x >> 3;
    int wg = (xg < r ? xg * (q + 1) : r * (q + 1) + (xg - r) * q) + o8;
    int row0 = (wg / 3) * 256, col0 = (wg % 3) * 256;
    f32x4 acc[8][4] = {};
    gemm256_pipe(A, Bm, row0, col0, 32799, wg & 3, acc, As, Bs);
    const int lane = threadIdx.x & 63, w = threadIdx.x >> 6;
    const int wr = w >> 2, wcn = w & 3;
    int cb = col0 + wcn * 64 + (lane & 15);
    float bj[4];
    #pragma unroll
    for (int n = 0; n < 4; ++n) bj[n] = bias[cb + n * 16];
    int rb = row0 + wr * 128 + 4 * (lane >> 4);
    #pragma unroll
    for (int m = 0; m < 8; ++m)
        #pragma unroll
        for (int i = 0; i < 4; ++i) {
            int rr = rb + m * 16 + i;
            if (rr >= BN_ROWS) continue;
            float* p = out + (size_t)rr * CC + cb;
            #pragma unroll
            for (int n = 0; n < 4; ++n) p[n * 16] = acc[m][n][i] + bj[n];
        }
}

// ---------------- qkv epilogue (fallback 128^2, 4 waves) ----------------
__device__ __forceinline__ void qkv_epilogue(f32x4 (&acc)[4][4], int row0, int col0,
                                             f16* __restrict__ q16, f16* __restrict__ k16,
                                             f16* __restrict__ v16t) {
    int lane = threadIdx.x & 63, wave = threadIdx.x >> 6;
    int wr = wave >> 1, wc = wave & 1;
    int rb = row0 + wr * 64 + 4 * (lane >> 4);
    int cb = col0 + wc * 64 + (lane & 15);
    #pragma unroll
    for (int m = 0; m < 4; ++m)
        #pragma unroll
        for (int n = 0; n < 4; ++n)
            #pragma unroll
            for (int i = 0; i < 4; ++i) {
                int r = rb + m * 16 + i;
                if (r >= BN_ROWS) continue;
                int j = cb + n * 16;
                int b = r / NTOK, nn = r - b * NTOK;
                int t = j / CC, rem = j - t * CC;
                int h = rem >> 6, d = rem & 63;
                size_t bh = (size_t)b * HH + h;
                f16 val = (f16)acc[m][n][i];
                if (t == 0) q16[(bh * NTOK + nn) * DD + d] = val;
                else if (t == 1) k16[(bh * NTOK + nn) * DD + d] = val;
                else v16t[(bh * DD + d) * VPAD + nn] = val;
            }
}

// fallback reg-staged qkv (f32 A), grid (257,18)
__global__ __launch_bounds__(256) void k_gemm_qkv_f32(const float* __restrict__ A, const f16* __restrict__ Bm,
                                                      f16* __restrict__ q16, f16* __restrict__ k16,
                                                      f16* __restrict__ v16t) {
    __shared__ __attribute__((aligned(16))) f16 As[128][LDSK];
    __shared__ __attribute__((aligned(16))) f16 Bs[128][LDSK];
    f32x4 acc[4][4] = {};
    int row0 = blockIdx.x * 128, col0 = blockIdx.y * 128;
    gemm128_core<true>(A, Bm, CC, row0, col0, BN_ROWS, acc, As, Bs);
    qkv_epilogue(acc, row0, col0, q16, k16, v16t);
}

// ---------------- STRING rotation (in-place on q16/k16) + norm_sq ----------------
__global__ __launch_bounds__(256) void k_rotate(const float* __restrict__ wcirc,
                                                f16* __restrict__ q16, f16* __restrict__ k16,
                                                float* __restrict__ nsqq, float* __restrict__ nsqk) {
    const int p = blockIdx.x, h = blockIdx.y;
    const int nn = p + 1;
    const int tid = threadIdx.x;
    __shared__ float wl[64];
    __shared__ __attribute__((aligned(16))) f16 Ws[64][72];
    __shared__ __attribute__((aligned(16))) f16 Xs[64][72];
    if (tid < 64) wl[tid] = wcirc[((size_t)h * 1024 + p) * 64 + tid];
    {   // stage rows: 0..31 = q(b), 32..63 = k(b)
        const int row = tid >> 2;
        const int ch = (tid & 3) * 16;
        const int b = row & 31;
        const f16* src = ((row < 32) ? q16 : k16) + (((size_t)b * HH + h) * NTOK + nn) * DD + ch;
        f16x8 v0 = *(const f16x8*)src;
        f16x8 v1 = *(const f16x8*)(src + 8);
        *(f16x8*)&Xs[row][ch] = v0;
        *(f16x8*)&Xs[row][ch + 8] = v1;
    }
    __syncthreads();
    #pragma unroll
    for (int j = 0; j < 16; ++j) {     // Ws[d][m] = w[(d-m) mod 64]
        int idx = tid * 16 + j;
        int d = idx >> 6, m = idx & 63;
        Ws[d][m] = (f16)wl[(d - m) & 63];
    }
    __syncthreads();
    const int lane = tid & 63, wave = tid >> 6;
    const int frow = lane & 15, fk = (lane >> 4) * 8;
    f32x4 acc[4] = {};
    #pragma unroll
    for (int kt = 0; kt < 64; kt += 32) {
        f16x8 a = *(const f16x8*)&Xs[wave * 16 + frow][kt + fk];
        #pragma unroll
        for (int n = 0; n < 4; ++n) {
            f16x8 bfr = *(const f16x8*)&Ws[n * 16 + frow][kt + fk];
            acc[n] = __builtin_amdgcn_mfma_f32_16x16x32_f16(a, bfr, acc[n], 0, 0, 0);
        }
    }
    #pragma unroll
    for (int i = 0; i < 4; ++i) {
        int row = wave * 16 + 4 * (lane >> 4) + i;
        int b = row & 31;
        f16* dst = ((row < 32) ? q16 : k16) + (((size_t)b * HH + h) * NTOK + nn) * DD;
        float ss = 0.f;
        #pragma unroll
        for (int n = 0; n < 4; ++n) {
            float v = acc[n][i];
            dst[n * 16 + (lane & 15)] = (f16)v;
            ss += v * v;
        }
        ss += __shfl_xor(ss, 1); ss += __shfl_xor(ss, 2);
        ss += __shfl_xor(ss, 4); ss += __shfl_xor(ss, 8);
        if ((lane & 15) == 0) {
            float* nd = (row < 32) ? nsqq : nsqk;
            nd[((size_t)b * HH + h) * NTOK + nn] = ss * (1.f / 16.f);  // 0.5 * D^-0.5
        }
    }
}

// ---------------- fused k-features -> context, m-split x2, dbuf single-barrier ----------------
__global__ __launch_bounds__(256) void k_fctx(const f16* __restrict__ k16, const f16* __restrict__ v16t,
                                              const f16* __restrict__ pfeat, const float* __restrict__ nsqk,
                                              f16* __restrict__ ctxT) {
    __shared__ __attribute__((aligned(16))) f16 uLDS[80 * 136];   // union fts[2][128][40] / cx[80][136]
    f16 (*fts)[128][LDSK] = (f16(*)[128][LDSK])uLDS;
    f16 (*cx)[136]        = (f16(*)[136])uLDS;
    const int bh = blockIdx.x;
    const int mh = blockIdx.y;                 // m-half 0/1
    const int tid = threadIdx.x;
    const int lane = tid & 63, w = tid >> 6;   // 4 waves
    const int frow = lane & 15, fk8 = (lane >> 4) * 8;
    const int ml0 = w * 32;                    // local m base
    const int m0 = mh * 128 + ml0;             // global m base
    f16x8 pf[2][2];
    #pragma unroll
    for (int mf = 0; mf < 2; ++mf)
        #pragma unroll
        for (int kf = 0; kf < 2; ++kf)
            pf[mf][kf] = *(const f16x8*)&pfeat[(m0 + mf * 16 + frow) * DD + kf * 32 + fk8];
    const f16* kb_base = k16 + (size_t)bh * NTOK * DD;
    const f16* vb_base = v16t + (size_t)bh * DD * VPAD;
    const float* ns_base = nsqk + (size_t)bh * NTOK;
    auto loadK = [&](f16x8 (&kb)[2][2], int n0) {
        #pragma unroll
        for (int nf = 0; nf < 2; ++nf) {
            int n = n0 + nf * 16 + frow;
            #pragma unroll
            for (int kf = 0; kf < 2; ++kf) {
                f16x8 z = {};
                if (n < NTOK) z = *(const f16x8*)&kb_base[(size_t)n * DD + kf * 32 + fk8];
                kb[nf][kf] = z;
            }
        }
    };
    f32x4 acc[2][5] = {};
    f16x8 kb[2][2];
    loadK(kb, 0);
    for (int n0 = 0; n0 < VPAD; n0 += 32) {
        const int cu = (n0 >> 5) & 1;
        f16x8 vb[4];
        #pragma unroll
        for (int ef = 0; ef < 4; ++ef)
            vb[ef] = *(const f16x8*)&vb_base[(size_t)(ef * 16 + frow) * VPAD + n0 + fk8];
        f32x4 fa[2][2] = {};
        #pragma unroll
        for (int kf = 0; kf < 2; ++kf)
            #pragma unroll
            for (int mf = 0; mf < 2; ++mf)
                #pragma unroll
                for (int nf = 0; nf < 2; ++nf)
                    fa[mf][nf] = __builtin_amdgcn_mfma_f32_16x16x32_f16(pf[mf][kf], kb[nf][kf], fa[mf][nf], 0, 0, 0);
        f16x8 kbn[2][2];
        loadK(kbn, n0 + 32);
        #pragma unroll
        for (int nf = 0; nf < 2; ++nf) {
            int ncol = n0 + nf * 16 + frow;
            float ns = (ncol < NTOK) ? ns_base[ncol] : 0.f;
            #pragma unroll
            for (int mf = 0; mf < 2; ++mf)
                #pragma unroll
                for (int i = 0; i < 4; ++i) {
                    int mloc = ml0 + mf * 16 + 4 * (lane >> 4) + i;
                    float v = (ncol < NTOK) ? fminf(__expf(fa[mf][nf][i] - ns), 60000.f) : 0.f;
                    fts[cu][mloc][nf * 16 + frow] = (f16)v;
                }
        }
        __syncthreads();          // single barrier: writes(cu) visible; next writes go to cu^1
        f16x8 afr[2];
        #pragma unroll
        for (int mf = 0; mf < 2; ++mf) afr[mf] = *(const f16x8*)&fts[cu][ml0 + mf * 16 + frow][fk8];
        #pragma unroll
        for (int ef = 0; ef < 4; ++ef)
            #pragma unroll
            for (int mf = 0; mf < 2; ++mf)
                acc[mf][ef] = __builtin_amdgcn_mfma_f32_16x16x32_f16(afr[mf], vb[ef], acc[mf][ef], 0, 0, 0);
        {   // ones row -> k_sum at e=64
            f16x8 bfr;
            #pragma unroll
            for (int j = 0; j < 8; ++j)
                bfr[j] = (f16)((frow == 0 && (n0 + fk8 + j) < NTOK) ? 1.f : 0.f);
            #pragma unroll
            for (int mf = 0; mf < 2; ++mf)
                acc[mf][4] = __builtin_amdgcn_mfma_f32_16x16x32_f16(afr[mf], bfr, acc[mf][4], 0, 0, 0);
        }
        #pragma unroll
        for (int nf = 0; nf < 2; ++nf)
            #pragma unroll
            for (int kf = 0; kf < 2; ++kf)
                kb[nf][kf] = kbn[nf][kf];
    }
    __syncthreads();   // all reads done before LDS reuse as cx
    #pragma unroll
    for (int mf = 0; mf < 2; ++mf)
        #pragma unroll
        for (int ef = 0; ef < 5; ++ef) {
            int e = ef * 16 + frow;
            f16x4 pk;
            #pragma unroll
            for (int i = 0; i < 4; ++i) pk[i] = (f16)acc[mf][ef][i];
            *(f16x4*)&cx[e][ml0 + mf * 16 + 4 * (lane >> 4)] = pk;
        }
    __syncthreads();
    for (int u = tid; u < 80 * 16; u += 256) {
        int e = u >> 4, seg = u & 15;
        *(f16x8*)&ctxT[((size_t)bh * 80 + e) * MM + mh * 128 + seg * 8] =
            *(const f16x8*)&cx[e][seg * 8];
    }
}

// ---------------- fused q-features -> num/den -> attn (grid: 9 x 384, 4 waves, dbuf) ----------------
__global__ __launch_bounds__(256) void k_fnum(const f16* __restrict__ q16, const f16* __restrict__ pfeat,
                                              const float* __restrict__ nsqq, const f16* __restrict__ ctxT,
                                              f16* __restrict__ attn) {
    __shared__ __attribute__((aligned(16))) f16 uLDS[2 * 128 * LDSK];  // union fts[2][128][40] / qe[128][72]
    f16 (*fts)[128][LDSK] = (f16(*)[128][LDSK])uLDS;
    f16 (*qe)[72]         = (f16(*)[72])uLDS;
    const int bh = blockIdx.y;
    const int b = bh / HH, h = bh - b * HH;
    const int t0 = blockIdx.x * 128;
    const int tid = threadIdx.x;
    const int lane = tid & 63, w = tid >> 6;
    const int frow = lane & 15, fk8 = (lane >> 4) * 8;
    const f16* qbase = q16 + (size_t)bh * NTOK * DD;
    const f16* cbase = ctxT + (size_t)bh * 80 * MM;
    f16x8 qa[2][2];
    float ns[2][4];
    #pragma unroll
    for (int tf = 0; tf < 2; ++tf) {
        int t = t0 + w * 32 + tf * 16 + frow;
        #pragma unroll
        for (int kf = 0; kf < 2; ++kf) {
            f16x8 z = {};
            if (t < NTOK) z = *(const f16x8*)&qbase[(size_t)t * DD + kf * 32 + fk8];
            qa[tf][kf] = z;
        }
        #pragma unroll
        for (int i = 0; i < 4; ++i) {
            int tr = t0 + w * 32 + tf * 16 + 4 * (lane >> 4) + i;
            ns[tf][i] = (tr < NTOK) ? nsqq[(size_t)bh * NTOK + tr] : 0.f;
        }
    }
    auto loadPB = [&](f16x8 (&pb)[2][2], int mc) {
        #pragma unroll
        for (int nf = 0; nf < 2; ++nf)
            #pragma unroll
            for (int kf = 0; kf < 2; ++kf)
                pb[nf][kf] = *(const f16x8*)&pfeat[(mc * 32 + nf * 16 + frow) * DD + kf * 32 + fk8];
    };
    f32x4 acc[2][5] = {};
    f16x8 pb[2][2];
    loadPB(pb, 0);
    #pragma unroll
    for (int mc = 0; mc < 8; ++mc) {
        const int cu = mc & 1;
        f32x4 fa[2][2] = {};
        #pragma unroll
        for (int kf = 0; kf < 2; ++kf)
            #pragma unroll
            for (int tf = 0; tf < 2; ++tf)
                #pragma unroll
                for (int nf = 0; nf < 2; ++nf)
                    fa[tf][nf] = __builtin_amdgcn_mfma_f32_16x16x32_f16(qa[tf][kf], pb[nf][kf], fa[tf][nf], 0, 0, 0);
        f16x8 pbn[2][2];
        loadPB(pbn, (mc + 1) & 7);
        f16x8 cbv[5];
        #pragma unroll
        for (int ef = 0; ef < 5; ++ef)
            cbv[ef] = *(const f16x8*)&cbase[(size_t)(ef * 16 + frow) * MM + mc * 32 + fk8];
        #pragma unroll
        for (int tf = 0; tf < 2; ++tf)
            #pragma unroll
            for (int nf = 0; nf < 2; ++nf)
                #pragma unroll
                for (int i = 0; i < 4; ++i) {
                    int tl = w * 32 + tf * 16 + 4 * (lane >> 4) + i;
                    float v = fminf(__expf(fa[tf][nf][i] - ns[tf][i]), 60000.f);
                    fts[cu][tl][nf * 16 + frow] = (f16)v;
                }
        __syncthreads();           // single barrier per mc (dbuf)
        f16x8 afr[2];
        #pragma unroll
        for (int tf = 0; tf < 2; ++tf) afr[tf] = *(const f16x8*)&fts[cu][w * 32 + tf * 16 + frow][fk8];
        #pragma unroll
        for (int ef = 0; ef < 5; ++ef)
            #pragma unroll
            for (int tf = 0; tf < 2; ++tf)
                acc[tf][ef] = __builtin_amdgcn_mfma_f32_16x16x32_f16(afr[tf], cbv[ef], acc[tf][ef], 0, 0, 0);
        #pragma unroll
        for (int nf = 0; nf < 2; ++nf)
            #pragma unroll
            for (int kf = 0; kf < 2; ++kf)
                pb[nf][kf] = pbn[nf][kf];
    }
    __syncthreads();   // all reads done before LDS reuse as qe
    #pragma unroll
    for (int tf = 0; tf < 2; ++tf)
        #pragma unroll
        for (int i = 0; i < 4; ++i) {
            float den = fmaxf(__shfl(acc[tf][4][i], lane & 48), 1e-6f);
            int tl = w * 32 + tf * 16 + 4 * (lane >> 4) + i;
            #pragma unroll
            for (int ef = 0; ef < 4; ++ef)
                qe[tl][ef * 16 + frow] = (f16)(acc[tf][ef][i] / den);
        }
    __syncthreads();
    for (int u = tid; u < 128 * 8; u += 256) {
        int tok = u >> 3, seg = u & 7;
        if (t0 + tok < NTOK)
            *(f16x8*)&attn[((size_t)(b * NTOK + t0 + tok)) * CC + h * DD + seg * 8] =
                *(const f16x8*)&qe[tok][seg * 8];
    }
}

// ---------------- fallback reg-staged proj ----------------
__device__ __forceinline__ void proj_epilogue(f32x4 (&acc)[4][4], int row0, int col0,
                                              const float* __restrict__ bias, float* __restrict__ out) {
    int lane = threadIdx.x & 63, wave = threadIdx.x >> 6;
    int wr = wave >> 1, wc = wave & 1;
    int rb = row0 + wr * 64 + 4 * (lane >> 4);
    int cb = col0 + wc * 64 + (lane & 15);
    #pragma unroll
    for (int n = 0; n < 4; ++n) {
        int j = cb + n * 16;
        float bj = bias[j];
        #pragma unroll
        for (int m = 0; m < 4; ++m)
            #pragma unroll
            for (int i = 0; i < 4; ++i) {
                int r = rb + m * 16 + i;
                if (r < BN_ROWS) out[(size_t)r * CC + j] = acc[m][n][i] + bj;
            }
    }
}

__global__ __launch_bounds__(256) void k_gemm_proj(const f16* __restrict__ A, const f16* __restrict__ Bm,
                                                   const float* __restrict__ bias, float* __restrict__ out) {
    __shared__ __attribute__((aligned(16))) f16 As[128][LDSK];
    __shared__ __attribute__((aligned(16))) f16 Bs[128][LDSK];
    f32x4 acc[4][4] = {};
    int row0 = blockIdx.x * 128, col0 = blockIdx.y * 128;
    gemm128_core<true>(A, Bm, CC, row0, col0, BN_ROWS, acc, As, Bs);
    proj_epilogue(acc, row0, col0, bias, out);
}

// ---------------- host ----------------
extern "C" void kernel_launch(void* const* d_in, const int* in_sizes, int n_in,
                              void* d_out, int out_size, void* d_ws, size_t ws_size,
                              hipStream_t stream) {
    const float* x = (const float*)d_in[0];
    const float* w_qkv = (const float*)d_in[1];
    const float* w_proj = (const float*)d_in[2];
    const float* b_proj = (const float*)d_in[3];
    const float* c_row = (const float*)d_in[4];
    const float* c_col = (const float*)d_in[5];
    const float* proj_feat = (const float*)d_in[6];
    float* out = (float*)d_out;
    char* ws = (char*)d_ws;
    char* ob = (char*)d_out;

    // ws layout
    const size_t O_WQKV  = 0;                        // 2304*768*2   = 3,538,944
    const size_t O_WPROJ = 3538944;                  // 768*768*2    = 1,179,648
    const size_t O_Q16   = 4718592;                  // 393600*64*2  = 50,380,800
    const size_t O_K16   = 55099392;                 // 50,380,800 (also attn alias)
    const size_t O_XW    = 105480192;                // 32896*768*2  = 50,528,256 (optional)
    const size_t NEED_B  = 105480192;
    const size_t NEED_A  = 156008448;
    if (ws_size < NEED_B) {
        k_diag<<<1, 64, 0, stream>>>(out, (float)((double)ws_size / 1048576.0));
        return;
    }
    const bool useA = (ws_size >= NEED_A);

    // d_out scratch layout (all dead before the final proj writes out)
    const size_t OD_V    = 0;                        // 384*64*1056*2 = 51,904,512
    const size_t OD_CTX  = 51904512;                 // 384*80*256*2  = 15,728,640
    const size_t OD_WC   = 67633152;                 // 3,145,728
    const size_t OD_NSQQ = 70778880;                 // 1,574,400
    const size_t OD_NSQK = 72353280;                 // 1,574,400
    const size_t OD_PF   = 73927680;                 // 32,768
    const size_t OD_AB   = 73960448;                 // 6,144

    f16* wqkv16  = (f16*)(ws + O_WQKV);
    f16* wproj16 = (f16*)(ws + O_WPROJ);
    f16* q16     = (f16*)(ws + O_Q16);
    f16* k16     = (f16*)(ws + O_K16);
    f16* xw16    = (f16*)(ws + O_XW);
    f16* v16t    = (f16*)(ob + OD_V);
    f16* ctxT    = (f16*)(ob + OD_CTX);
    float* wcirc = (float*)(ob + OD_WC);
    float* nsqq  = (float*)(ob + OD_NSQQ);
    float* nsqk  = (float*)(ob + OD_NSQK);
    f16* pfeat16 = (f16*)(ob + OD_PF);
    float* ab    = (float*)(ob + OD_AB);
    f16* attn16  = k16;   // k16 dead after k_fctx

    // conversions & precompute (merged)
    k_prep<<<9280, 256, 0, stream>>>(w_qkv, w_proj, proj_feat, wqkv16, wproj16, pfeat16);
    k_ab<<<12, 64, 0, stream>>>(c_row, c_col, ab);
    k_wcirc<<<3072, 256, 0, stream>>>(ab, wcirc);

    // qkv GEMM + scatter
    if (useA) {
        k_cvt_x<<<24672, 256, 0, stream>>>(x, xw16);
        k_gemm_qkv_256<<<1161, 512, 0, stream>>>(xw16, wqkv16, q16, k16, v16t);
    } else {
        k_gemm_qkv_f32<<<dim3(257, 18), 256, 0, stream>>>(x, wqkv16, q16, k16, v16t);
    }
    // zero v16t pad columns + CLS norm_sq (merged)
    k_post<<<576, 256, 0, stream>>>(v16t, q16, k16, nsqq, nsqk);

    // STRING rotation (in-place)
    k_rotate<<<dim3(1024, 12), 256, 0, stream>>>(wcirc, q16, k16, nsqq, nsqk);

    // fused pipelines (fctx m-split x2 for CU balance)
    k_fctx<<<dim3(384, 2), 256, 0, stream>>>(k16, v16t, pfeat16, nsqk, ctxT);
    k_fnum<<<dim3(9, 384), 256, 0, stream>>>(q16, pfeat16, nsqq, ctxT, attn16);

    // output projection (overwrites all d_out scratch)
    if (useA) {
        k_gemm_proj_256<<<387, 512, 0, stream>>>(attn16, wproj16, b_proj, out);
    } else {
        k_gemm_proj<<<dim3(257, 6), 256, 0, stream>>>(attn16, wproj16, b_proj, out);
    }

    (void)in_sizes; (void)n_in; (void)out_size;
}

// Round 16
// 585.095 us; speedup vs baseline: 1.0079x; 1.0079x over previous
//
#include <hip/hip_runtime.h>
#include <math.h>

typedef _Float16 f16;
typedef _Float16 f16x8 __attribute__((ext_vector_type(8)));
typedef _Float16 f16x4 __attribute__((ext_vector_type(4)));
typedef float f32x4 __attribute__((ext_vector_type(4)));

#define LDSK 40          // 32 + 8 pad for staged feat tiles
#define NTOK 1025
#define CC 768
#define HH 12
#define DD 64
#define MM 256
#define VPAD 1056        // 33*32 padded token count for vT
#define BN_ROWS 32800    // 32*1025

// ---------------- staging loads: 16 f16; f32 converts on the fly ----------------
__device__ __forceinline__ void load_row16(const f16* p, f16x8& a0, f16x8& a1) {
    a0 = *(const f16x8*)p;
    a1 = *(const f16x8*)(p + 8);
}
__device__ __forceinline__ void load_row16(const float* p, f16x8& a0, f16x8& a1) {
    const float4* q = (const float4*)p;
    float4 u0 = q[0], u1 = q[1], u2 = q[2], u3 = q[3];
    a0[0] = (f16)u0.x; a0[1] = (f16)u0.y; a0[2] = (f16)u0.z; a0[3] = (f16)u0.w;
    a0[4] = (f16)u1.x; a0[5] = (f16)u1.y; a0[6] = (f16)u1.z; a0[7] = (f16)u1.w;
    a1[0] = (f16)u2.x; a1[1] = (f16)u2.y; a1[2] = (f16)u2.z; a1[3] = (f16)u2.w;
    a1[4] = (f16)u3.x; a1[5] = (f16)u3.y; a1[6] = (f16)u3.z; a1[7] = (f16)u3.w;
}

// async global->LDS, 16B per lane, LDS dest wave-uniform base + lane*16
__device__ __forceinline__ void gload16(const f16* g, f16* l) {
    __builtin_amdgcn_global_load_lds(
        (const __attribute__((address_space(1))) unsigned int*)g,
        (__attribute__((address_space(3))) unsigned int*)l, 16, 0, 0);
}

// ---------------- small kernels ----------------
__global__ void k_diag(float* out, float v) {
    if (threadIdx.x == 0 && blockIdx.x == 0) out[0] = v;
}

__global__ __launch_bounds__(256) void k_cvt_x(const float* __restrict__ x, f16* __restrict__ xw) {
    size_t i = ((size_t)blockIdx.x * 256 + threadIdx.x) * 4;   // covers 32896*768
    float4 v;
    if (i < (size_t)BN_ROWS * CC) v = *(const float4*)(x + i);
    else v = make_float4(0.f, 0.f, 0.f, 0.f);
    f16x4 o; o[0] = (f16)v.x; o[1] = (f16)v.y; o[2] = (f16)v.z; o[3] = (f16)v.w;
    *(f16x4*)(xw + i) = o;
}

// merged: [0,6912) wqkv cvt, [6912,9216) wproj cvt, [9216,9280) pfeat cvt, [9280,9292) ab
__global__ __launch_bounds__(256) void k_prep(const float* __restrict__ w_qkv, const float* __restrict__ w_proj,
                                              const float* __restrict__ proj_feat,
                                              const float* __restrict__ c_row, const float* __restrict__ c_col,
                                              f16* __restrict__ wqkv16, f16* __restrict__ wproj16,
                                              f16* __restrict__ pfeat16, float* __restrict__ ab) {
    int b = blockIdx.x;
    if (b < 6912) {
        long j = (long)b * 256 + threadIdx.x;
        wqkv16[j] = (f16)w_qkv[j];
    } else if (b < 9216) {
        long j = (long)(b - 6912) * 256 + threadIdx.x;
        wproj16[j] = (f16)w_proj[j];
    } else if (b < 9280) {
        long j = (long)(b - 9216) * 256 + threadIdx.x;
        pfeat16[j] = (f16)(proj_feat[j] * 0.3535533906f);   // fold D^-0.25
    } else if (threadIdx.x < 64) {
        int h = b - 9280, k = threadIdx.x;
        float sa = 0.f, sb = 0.f;
        for (int d = 0; d < 64; ++d) {
            float s = sinf((float)((k * d) & 63) * (6.283185307179586f / 64.f));
            sa += c_row[h * 64 + d] * s;
            sb += c_col[h * 64 + d] * s;
        }
        ab[h * 64 + k] = -2.f * sa;
        ab[768 + h * 64 + k] = -2.f * sb;
    }
}

// merged post-qkv: [0,384) zero v16t pad cols; [384,576) CLS norm_sq
__global__ __launch_bounds__(256) void k_post(f16* __restrict__ v16t,
                                              const f16* __restrict__ q16, const f16* __restrict__ k16,
                                              float* __restrict__ nsqq, float* __restrict__ nsqk) {
    int blk = blockIdx.x;
    if (blk < 384) {
        int bh = blk;
        for (int u = threadIdx.x; u < 64 * 31; u += 256) {
            int d = u / 31, j = u - d * 31;
            v16t[((size_t)bh * DD + d) * VPAD + 1025 + j] = (f16)0.f;
        }
    } else {
        int gw = ((blk - 384) * 256 + threadIdx.x) >> 6;   // 0..767
        int lane = threadIdx.x & 63;
        int which = gw & 1; int bh = gw >> 1;
        const f16* src = (which ? k16 : q16) + (size_t)bh * NTOK * DD;
        float v = (float)src[lane];
        float ss = v * v;
        for (int off = 1; off < 64; off <<= 1) ss += __shfl_xor(ss, off);
        if (lane == 0) (which ? nsqk : nsqq)[(size_t)bh * NTOK] = ss * (1.f / 16.f);
    }
}

// w[h,p,t] = (1/64) * sum_k cos(theta_k + 2*pi*k*t/64); 4 hp per 256-thread block
__global__ __launch_bounds__(256) void k_wcirc(const float* __restrict__ ab, float* __restrict__ wc) {
    int grp = threadIdx.x >> 6;
    int t = threadIdx.x & 63;
    int hp = blockIdx.x * 4 + grp;                 // grid 3072
    int h = hp >> 10; int p = hp & 1023;
    float pr = (float)(p >> 5), pc = (float)(p & 31);
    __shared__ float th[4][64];
    th[grp][t] = pr * ab[h * 64 + t] + pc * ab[768 + h * 64 + t];
    __syncthreads();
    float s = 0.f;
    #pragma unroll 8
    for (int k = 0; k < 64; ++k) {
        float arg = th[grp][k] + (float)((k * t) & 63) * (6.283185307179586f / 64.f);
        s += __cosf(arg);
    }
    wc[(size_t)hp * 64 + t] = s * (1.f / 64.f);
}

// ---------------- legacy reg-staged 128x128 core (fallback path) ----------------
template <bool GA, typename TA, typename TB>
__device__ __forceinline__ void gemm128_core(const TA* __restrict__ A, const TB* __restrict__ Bm,
                                             int K, int row0, int col0, int Alim,
                                             f32x4 (&acc)[4][4],
                                             f16 (*As)[LDSK], f16 (*Bs)[LDSK]) {
    const int tid = threadIdx.x;
    const int lane = tid & 63;
    const int lr = tid >> 1, lk = (tid & 1) * 16;
    const int frow = lane & 15, fk = (lane >> 4) * 8;
    const int wave = tid >> 6, wr = wave >> 1, wc = wave & 1;
    for (int kt = 0; kt < K; kt += 32) {
        f16x8 a0 = {}, a1 = {}, b0, b1;
        if (!GA || (row0 + lr) < Alim)
            load_row16(A + (size_t)(row0 + lr) * K + kt + lk, a0, a1);
        load_row16(Bm + (size_t)(col0 + lr) * K + kt + lk, b0, b1);
        __syncthreads();
        *(f16x8*)&As[lr][lk] = a0; *(f16x8*)&As[lr][lk + 8] = a1;
        *(f16x8*)&Bs[lr][lk] = b0; *(f16x8*)&Bs[lr][lk + 8] = b1;
        __syncthreads();
        f16x8 af[4], bf[4];
        #pragma unroll
        for (int m = 0; m < 4; ++m) af[m] = *(const f16x8*)&As[wr * 64 + m * 16 + frow][fk];
        #pragma unroll
        for (int n = 0; n < 4; ++n) bf[n] = *(const f16x8*)&Bs[wc * 64 + n * 16 + frow][fk];
        #pragma unroll
        for (int m = 0; m < 4; ++m)
            #pragma unroll
            for (int n = 0; n < 4; ++n)
                acc[m][n] = __builtin_amdgcn_mfma_f32_16x16x32_f16(af[m], bf[n], acc[m][n], 0, 0, 0);
    }
}

// ---------------- 256x256 DMA-staged core: BK=64, T2 swizzle, dbuf (round-12 best) ----------------
__device__ __forceinline__ void gemm256_pipe(const f16* __restrict__ A, const f16* __restrict__ Bm,
                                             int row0, int col0, int aclamp,
                                             f32x4 (&acc)[8][4], f16* As, f16* Bs) {
    const int tid = threadIdx.x;
    const int lane = tid & 63, w = tid >> 6;
    const int frow = lane & 15;
    const int srow = lane >> 3;                       // 8 rows x 128B per wave-issue
    const int schk = ((lane & 7) ^ srow) * 8;         // inverse-swizzled source col (f16)
    const f16* aG[4]; const f16* bG[4];
    f16* aL[4]; f16* bL[4];
    #pragma unroll
    for (int j = 0; j < 4; ++j) {
        int ra = row0 + w * 32 + 8 * j + srow;
        if (ra > aclamp) ra = aclamp;                 // clamped rows are masked in epilogue
        aG[j] = A + (size_t)ra * CC + schk;
        bG[j] = Bm + (size_t)(col0 + w * 32 + 8 * j + srow) * CC + schk;
        aL[j] = As + (w * 32 + 8 * j) * 64;
        bL[j] = Bs + (w * 32 + 8 * j) * 64;
    }
    auto STAGE = [&](int tt) {
        int bo = (tt & 1) * 16384, ko = tt * 64;
        #pragma unroll
        for (int j = 0; j < 4; ++j) {
            gload16(aG[j] + ko, aL[j] + bo);
            gload16(bG[j] + ko, bL[j] + bo);
        }
    };
    STAGE(0);
    const int wr = w >> 2, wcn = w & 3;
    const int fk8 = (lane >> 4) * 8;
    const int cswz = (frow & 7) * 8;
    for (int t = 0; t < 12; ++t) {
        asm volatile("s_waitcnt vmcnt(0)" ::: "memory");   // tile t landed (issued iter t-1)
        __builtin_amdgcn_s_barrier();
        __builtin_amdgcn_sched_barrier(0);                 // nothing crosses the barrier
        if (t < 11) STAGE(t + 1);                          // fly next tile under this compute
        const f16* Ac = As + (t & 1) * 16384;
        const f16* Bc = Bs + (t & 1) * 16384;
        #pragma unroll
        for (int ks = 0; ks < 2; ++ks) {
            const int co = (ks * 32 + fk8) ^ cswz;
            f16x8 af[8], bf[4];
            #pragma unroll
            for (int n = 0; n < 4; ++n)
                bf[n] = *(const f16x8*)&Bc[(wcn * 64 + n * 16 + frow) * 64 + co];
            #pragma unroll
            for (int m = 0; m < 8; ++m)
                af[m] = *(const f16x8*)&Ac[(wr * 128 + m * 16 + frow) * 64 + co];
            #pragma unroll
            for (int n = 0; n < 4; ++n)
                #pragma unroll
                for (int m = 0; m < 8; ++m)
                    acc[m][n] = __builtin_amdgcn_mfma_f32_16x16x32_f16(af[m], bf[n], acc[m][n], 0, 0, 0);
        }
    }
}

// 256^2 qkv: 1-D grid 1161 = 129 x 9, bijective XCD swizzle, col-tile fastest
__global__ __launch_bounds__(512, 2) void k_gemm_qkv_256(const f16* __restrict__ A, const f16* __restrict__ Bm,
                                                         f16* __restrict__ q16, f16* __restrict__ k16,
                                                         f16* __restrict__ v16t) {
    __shared__ __attribute__((aligned(16))) f16 As[2 * 256 * 64];
    __shared__ __attribute__((aligned(16))) f16 Bs[2 * 256 * 64];
    const int q = 145, r = 1;                       // nwg = 1161
    int xg = blockIdx.x & 7, o8 = blockIdx.x >> 3;
    int wg = (xg < r ? xg * (q + 1) : r * (q + 1) + (xg - r) * q) + o8;
    int row0 = (wg / 9) * 256, col0 = (wg % 9) * 256;
    f32x4 acc[8][4] = {};
    gemm256_pipe(A, Bm, row0, col0, 32895, acc, As, Bs);
    // epilogue: per-wave constant (t, h); scatter into q16/k16/v16t
    const int lane = threadIdx.x & 63, w = threadIdx.x >> 6;
    const int wr = w >> 2, wcn = w & 3;
    int cb = col0 + wcn * 64 + (lane & 15);
    int tt = cb / CC;
    int h = (cb - tt * CC) >> 6;
    int d0 = lane & 15;
    int rb = row0 + wr * 128 + 4 * (lane >> 4);
    #pragma unroll
    for (int m = 0; m < 8; ++m)
        #pragma unroll
        for (int i = 0; i < 4; ++i) {
            int rr = rb + m * 16 + i;
            if (rr >= BN_ROWS) continue;
            int b = rr / NTOK, nn = rr - b * NTOK;
            size_t bh = (size_t)b * HH + h;
            if (tt == 0) {
                f16* p = q16 + (bh * NTOK + nn) * DD + d0;
                #pragma unroll
                for (int n = 0; n < 4; ++n) p[n * 16] = (f16)acc[m][n][i];
            } else if (tt == 1) {
                f16* p = k16 + (bh * NTOK + nn) * DD + d0;
                #pragma unroll
                for (int n = 0; n < 4; ++n) p[n * 16] = (f16)acc[m][n][i];
            } else {
                f16* p = v16t + (bh * DD + d0) * VPAD + nn;
                #pragma unroll
                for (int n = 0; n < 4; ++n) p[(size_t)n * 16 * VPAD] = (f16)acc[m][n][i];
            }
        }
}

// 256^2 proj: 1-D grid 387 = 129 x 3, bijective XCD swizzle
__global__ __launch_bounds__(512, 2) void k_gemm_proj_256(const f16* __restrict__ A, const f16* __restrict__ Bm,
                                                          const float* __restrict__ bias, float* __restrict__ out) {
    __shared__ __attribute__((aligned(16))) f16 As[2 * 256 * 64];
    __shared__ __attribute__((aligned(16))) f16 Bs[2 * 256 * 64];
    const int q = 48, r = 3;                        // nwg = 387
    int xg = blockIdx.x & 7, o8 = blockIdx.x >> 3;
    int wg = (xg < r ? xg * (q + 1) : r * (q + 1) + (xg - r) * q) + o8;
    int row0 = (wg / 3) * 256, col0 = (wg % 3) * 256;
    f32x4 acc[8][4] = {};
    gemm256_pipe(A, Bm, row0, col0, 32799, acc, As, Bs);
    const int lane = threadIdx.x & 63, w = threadIdx.x >> 6;
    const int wr = w >> 2, wcn = w & 3;
    int cb = col0 + wcn * 64 + (lane & 15);
    float bj[4];
    #pragma unroll
    for (int n = 0; n < 4; ++n) bj[n] = bias[cb + n * 16];
    int rb = row0 + wr * 128 + 4 * (lane >> 4);
    #pragma unroll
    for (int m = 0; m < 8; ++m)
        #pragma unroll
        for (int i = 0; i < 4; ++i) {
            int rr = rb + m * 16 + i;
            if (rr >= BN_ROWS) continue;
            float* p = out + (size_t)rr * CC + cb;
            #pragma unroll
            for (int n = 0; n < 4; ++n) p[n * 16] = acc[m][n][i] + bj[n];
        }
}

// ---------------- qkv epilogue (fallback 128^2, 4 waves) ----------------
__device__ __forceinline__ void qkv_epilogue(f32x4 (&acc)[4][4], int row0, int col0,
                                             f16* __restrict__ q16, f16* __restrict__ k16,
                                             f16* __restrict__ v16t) {
    int lane = threadIdx.x & 63, wave = threadIdx.x >> 6;
    int wr = wave >> 1, wc = wave & 1;
    int rb = row0 + wr * 64 + 4 * (lane >> 4);
    int cb = col0 + wc * 64 + (lane & 15);
    #pragma unroll
    for (int m = 0; m < 4; ++m)
        #pragma unroll
        for (int n = 0; n < 4; ++n)
            #pragma unroll
            for (int i = 0; i < 4; ++i) {
                int r = rb + m * 16 + i;
                if (r >= BN_ROWS) continue;
                int j = cb + n * 16;
                int b = r / NTOK, nn = r - b * NTOK;
                int t = j / CC, rem = j - t * CC;
                int h = rem >> 6, d = rem & 63;
                size_t bh = (size_t)b * HH + h;
                f16 val = (f16)acc[m][n][i];
                if (t == 0) q16[(bh * NTOK + nn) * DD + d] = val;
                else if (t == 1) k16[(bh * NTOK + nn) * DD + d] = val;
                else v16t[(bh * DD + d) * VPAD + nn] = val;
            }
}

// fallback reg-staged qkv (f32 A), grid (257,18)
__global__ __launch_bounds__(256) void k_gemm_qkv_f32(const float* __restrict__ A, const f16* __restrict__ Bm,
                                                      f16* __restrict__ q16, f16* __restrict__ k16,
                                                      f16* __restrict__ v16t) {
    __shared__ __attribute__((aligned(16))) f16 As[128][LDSK];
    __shared__ __attribute__((aligned(16))) f16 Bs[128][LDSK];
    f32x4 acc[4][4] = {};
    int row0 = blockIdx.x * 128, col0 = blockIdx.y * 128;
    gemm128_core<true>(A, Bm, CC, row0, col0, BN_ROWS, acc, As, Bs);
    qkv_epilogue(acc, row0, col0, q16, k16, v16t);
}

// ---------------- STRING rotation (in-place on q16/k16) + norm_sq ----------------
__global__ __launch_bounds__(256) void k_rotate(const float* __restrict__ wcirc,
                                                f16* __restrict__ q16, f16* __restrict__ k16,
                                                float* __restrict__ nsqq, float* __restrict__ nsqk) {
    const int p = blockIdx.x, h = blockIdx.y;
    const int nn = p + 1;
    const int tid = threadIdx.x;
    __shared__ float wl[64];
    __shared__ __attribute__((aligned(16))) f16 Ws[64][72];
    __shared__ __attribute__((aligned(16))) f16 Xs[64][72];
    if (tid < 64) wl[tid] = wcirc[((size_t)h * 1024 + p) * 64 + tid];
    {   // stage rows: 0..31 = q(b), 32..63 = k(b)
        const int row = tid >> 2;
        const int ch = (tid & 3) * 16;
        const int b = row & 31;
        const f16* src = ((row < 32) ? q16 : k16) + (((size_t)b * HH + h) * NTOK + nn) * DD + ch;
        f16x8 v0 = *(const f16x8*)src;
        f16x8 v1 = *(const f16x8*)(src + 8);
        *(f16x8*)&Xs[row][ch] = v0;
        *(f16x8*)&Xs[row][ch + 8] = v1;
    }
    __syncthreads();
    #pragma unroll
    for (int j = 0; j < 16; ++j) {     // Ws[d][m] = w[(d-m) mod 64]
        int idx = tid * 16 + j;
        int d = idx >> 6, m = idx & 63;
        Ws[d][m] = (f16)wl[(d - m) & 63];
    }
    __syncthreads();
    const int lane = tid & 63, wave = tid >> 6;
    const int frow = lane & 15, fk = (lane >> 4) * 8;
    f32x4 acc[4] = {};
    #pragma unroll
    for (int kt = 0; kt < 64; kt += 32) {
        f16x8 a = *(const f16x8*)&Xs[wave * 16 + frow][kt + fk];
        #pragma unroll
        for (int n = 0; n < 4; ++n) {
            f16x8 bfr = *(const f16x8*)&Ws[n * 16 + frow][kt + fk];
            acc[n] = __builtin_amdgcn_mfma_f32_16x16x32_f16(a, bfr, acc[n], 0, 0, 0);
        }
    }
    #pragma unroll
    for (int i = 0; i < 4; ++i) {
        int row = wave * 16 + 4 * (lane >> 4) + i;
        int b = row & 31;
        f16* dst = ((row < 32) ? q16 : k16) + (((size_t)b * HH + h) * NTOK + nn) * DD;
        float ss = 0.f;
        #pragma unroll
        for (int n = 0; n < 4; ++n) {
            float v = acc[n][i];
            dst[n * 16 + (lane & 15)] = (f16)v;
            ss += v * v;
        }
        ss += __shfl_xor(ss, 1); ss += __shfl_xor(ss, 2);
        ss += __shfl_xor(ss, 4); ss += __shfl_xor(ss, 8);
        if ((lane & 15) == 0) {
            float* nd = (row < 32) ? nsqq : nsqk;
            nd[((size_t)b * HH + h) * NTOK + nn] = ss * (1.f / 16.f);  // 0.5 * D^-0.5
        }
    }
}

// ---------------- fused k-features -> context, m-split x2, dbuf single-barrier ----------------
__global__ __launch_bounds__(256) void k_fctx(const f16* __restrict__ k16, const f16* __restrict__ v16t,
                                              const f16* __restrict__ pfeat, const float* __restrict__ nsqk,
                                              f16* __restrict__ ctxT) {
    __shared__ __attribute__((aligned(16))) f16 uLDS[80 * 136];   // union fts[2][128][40] / cx[80][136]
    f16 (*fts)[128][LDSK] = (f16(*)[128][LDSK])uLDS;
    f16 (*cx)[136]        = (f16(*)[136])uLDS;
    const int bh = blockIdx.x;
    const int mh = blockIdx.y;                 // m-half 0/1
    const int tid = threadIdx.x;
    const int lane = tid & 63, w = tid >> 6;   // 4 waves
    const int frow = lane & 15, fk8 = (lane >> 4) * 8;
    const int ml0 = w * 32;                    // local m base
    const int m0 = mh * 128 + ml0;             // global m base
    f16x8 pf[2][2];
    #pragma unroll
    for (int mf = 0; mf < 2; ++mf)
        #pragma unroll
        for (int kf = 0; kf < 2; ++kf)
            pf[mf][kf] = *(const f16x8*)&pfeat[(m0 + mf * 16 + frow) * DD + kf * 32 + fk8];
    const f16* kb_base = k16 + (size_t)bh * NTOK * DD;
    const f16* vb_base = v16t + (size_t)bh * DD * VPAD;
    const float* ns_base = nsqk + (size_t)bh * NTOK;
    auto loadK = [&](f16x8 (&kb)[2][2], int n0) {
        #pragma unroll
        for (int nf = 0; nf < 2; ++nf) {
            int n = n0 + nf * 16 + frow;
            #pragma unroll
            for (int kf = 0; kf < 2; ++kf) {
                f16x8 z = {};
                if (n < NTOK) z = *(const f16x8*)&kb_base[(size_t)n * DD + kf * 32 + fk8];
                kb[nf][kf] = z;
            }
        }
    };
    f32x4 acc[2][5] = {};
    f16x8 kb[2][2];
    loadK(kb, 0);
    for (int n0 = 0; n0 < VPAD; n0 += 32) {
        const int cu = (n0 >> 5) & 1;
        f16x8 vb[4];
        #pragma unroll
        for (int ef = 0; ef < 4; ++ef)
            vb[ef] = *(const f16x8*)&vb_base[(size_t)(ef * 16 + frow) * VPAD + n0 + fk8];
        f32x4 fa[2][2] = {};
        #pragma unroll
        for (int kf = 0; kf < 2; ++kf)
            #pragma unroll
            for (int mf = 0; mf < 2; ++mf)
                #pragma unroll
                for (int nf = 0; nf < 2; ++nf)
                    fa[mf][nf] = __builtin_amdgcn_mfma_f32_16x16x32_f16(pf[mf][kf], kb[nf][kf], fa[mf][nf], 0, 0, 0);
        f16x8 kbn[2][2];
        loadK(kbn, n0 + 32);
        #pragma unroll
        for (int nf = 0; nf < 2; ++nf) {
            int ncol = n0 + nf * 16 + frow;
            float ns = (ncol < NTOK) ? ns_base[ncol] : 0.f;
            #pragma unroll
            for (int mf = 0; mf < 2; ++mf)
                #pragma unroll
                for (int i = 0; i < 4; ++i) {
                    int mloc = ml0 + mf * 16 + 4 * (lane >> 4) + i;
                    float v = (ncol < NTOK) ? fminf(__expf(fa[mf][nf][i] - ns), 60000.f) : 0.f;
                    fts[cu][mloc][nf * 16 + frow] = (f16)v;
                }
        }
        __syncthreads();          // single barrier: writes(cu) visible; next writes go to cu^1
        f16x8 afr[2];
        #pragma unroll
        for (int mf = 0; mf < 2; ++mf) afr[mf] = *(const f16x8*)&fts[cu][ml0 + mf * 16 + frow][fk8];
        #pragma unroll
        for (int ef = 0; ef < 4; ++ef)
            #pragma unroll
            for (int mf = 0; mf < 2; ++mf)
                acc[mf][ef] = __builtin_amdgcn_mfma_f32_16x16x32_f16(afr[mf], vb[ef], acc[mf][ef], 0, 0, 0);
        {   // ones row -> k_sum at e=64
            f16x8 bfr;
            #pragma unroll
            for (int j = 0; j < 8; ++j)
                bfr[j] = (f16)((frow == 0 && (n0 + fk8 + j) < NTOK) ? 1.f : 0.f);
            #pragma unroll
            for (int mf = 0; mf < 2; ++mf)
                acc[mf][4] = __builtin_amdgcn_mfma_f32_16x16x32_f16(afr[mf], bfr, acc[mf][4], 0, 0, 0);
        }
        #pragma unroll
        for (int nf = 0; nf < 2; ++nf)
            #pragma unroll
            for (int kf = 0; kf < 2; ++kf)
                kb[nf][kf] = kbn[nf][kf];
    }
    __syncthreads();   // all reads done before LDS reuse as cx
    #pragma unroll
    for (int mf = 0; mf < 2; ++mf)
        #pragma unroll
        for (int ef = 0; ef < 5; ++ef) {
            int e = ef * 16 + frow;
            f16x4 pk;
            #pragma unroll
            for (int i = 0; i < 4; ++i) pk[i] = (f16)acc[mf][ef][i];
            *(f16x4*)&cx[e][ml0 + mf * 16 + 4 * (lane >> 4)] = pk;
        }
    __syncthreads();
    for (int u = tid; u < 80 * 16; u += 256) {
        int e = u >> 4, seg = u & 15;
        *(f16x8*)&ctxT[((size_t)bh * 80 + e) * MM + mh * 128 + seg * 8] =
            *(const f16x8*)&cx[e][seg * 8];
    }
}

// ---------------- fused q-features -> num/den -> attn (grid: 9 x 384, 4 waves, dbuf) ----------------
// last t0-tile clamped to NTOK-128: overlap tokens recomputed with identical values (benign)
__global__ __launch_bounds__(256) void k_fnum(const f16* __restrict__ q16, const f16* __restrict__ pfeat,
                                              const float* __restrict__ nsqq, const f16* __restrict__ ctxT,
                                              f16* __restrict__ attn) {
    __shared__ __attribute__((aligned(16))) f16 uLDS[2 * 128 * LDSK];  // union fts[2][128][40] / qe[128][72]
    f16 (*fts)[128][LDSK] = (f16(*)[128][LDSK])uLDS;
    f16 (*qe)[72]         = (f16(*)[72])uLDS;
    const int bh = blockIdx.y;
    const int b = bh / HH, h = bh - b * HH;
    int t0 = blockIdx.x * 128;
    if (t0 + 128 > NTOK) t0 = NTOK - 128;      // clamp: full tile of real tokens
    const int tid = threadIdx.x;
    const int lane = tid & 63, w = tid >> 6;
    const int frow = lane & 15, fk8 = (lane >> 4) * 8;
    const f16* qbase = q16 + (size_t)bh * NTOK * DD;
    const f16* cbase = ctxT + (size_t)bh * 80 * MM;
    f16x8 qa[2][2];
    float ns[2][4];
    #pragma unroll
    for (int tf = 0; tf < 2; ++tf) {
        int t = t0 + w * 32 + tf * 16 + frow;
        #pragma unroll
        for (int kf = 0; kf < 2; ++kf)
            qa[tf][kf] = *(const f16x8*)&qbase[(size_t)t * DD + kf * 32 + fk8];
        #pragma unroll
        for (int i = 0; i < 4; ++i) {
            int tr = t0 + w * 32 + tf * 16 + 4 * (lane >> 4) + i;
            ns[tf][i] = nsqq[(size_t)bh * NTOK + tr];
        }
    }
    auto loadPB = [&](f16x8 (&pb)[2][2], int mc) {
        #pragma unroll
        for (int nf = 0; nf < 2; ++nf)
            #pragma unroll
            for (int kf = 0; kf < 2; ++kf)
                pb[nf][kf] = *(const f16x8*)&pfeat[(mc * 32 + nf * 16 + frow) * DD + kf * 32 + fk8];
    };
    f32x4 acc[2][5] = {};
    f16x8 pb[2][2];
    loadPB(pb, 0);
    #pragma unroll
    for (int mc = 0; mc < 8; ++mc) {
        const int cu = mc & 1;
        f32x4 fa[2][2] = {};
        #pragma unroll
        for (int kf = 0; kf < 2; ++kf)
            #pragma unroll
            for (int tf = 0; tf < 2; ++tf)
                #pragma unroll
                for (int nf = 0; nf < 2; ++nf)
                    fa[tf][nf] = __builtin_amdgcn_mfma_f32_16x16x32_f16(qa[tf][kf], pb[nf][kf], fa[tf][nf], 0, 0, 0);
        f16x8 pbn[2][2];
        loadPB(pbn, (mc + 1) & 7);
        f16x8 cbv[5];
        #pragma unroll
        for (int ef = 0; ef < 5; ++ef)
            cbv[ef] = *(const f16x8*)&cbase[(size_t)(ef * 16 + frow) * MM + mc * 32 + fk8];
        #pragma unroll
        for (int tf = 0; tf < 2; ++tf)
            #pragma unroll
            for (int nf = 0; nf < 2; ++nf)
                #pragma unroll
                for (int i = 0; i < 4; ++i) {
                    int tl = w * 32 + tf * 16 + 4 * (lane >> 4) + i;
                    float v = fminf(__expf(fa[tf][nf][i] - ns[tf][i]), 60000.f);
                    fts[cu][tl][nf * 16 + frow] = (f16)v;
                }
        __syncthreads();           // single barrier per mc (dbuf)
        f16x8 afr[2];
        #pragma unroll
        for (int tf = 0; tf < 2; ++tf) afr[tf] = *(const f16x8*)&fts[cu][w * 32 + tf * 16 + frow][fk8];
        #pragma unroll
        for (int ef = 0; ef < 5; ++ef)
            #pragma unroll
            for (int tf = 0; tf < 2; ++tf)
                acc[tf][ef] = __builtin_amdgcn_mfma_f32_16x16x32_f16(afr[tf], cbv[ef], acc[tf][ef], 0, 0, 0);
        #pragma unroll
        for (int nf = 0; nf < 2; ++nf)
            #pragma unroll
            for (int kf = 0; kf < 2; ++kf)
                pb[nf][kf] = pbn[nf][kf];
    }
    __syncthreads();   // all reads done before LDS reuse as qe
    #pragma unroll
    for (int tf = 0; tf < 2; ++tf)
        #pragma unroll
        for (int i = 0; i < 4; ++i) {
            float den = fmaxf(__shfl(acc[tf][4][i], lane & 48), 1e-6f);
            int tl = w * 32 + tf * 16 + 4 * (lane >> 4) + i;
            #pragma unroll
            for (int ef = 0; ef < 4; ++ef)
                qe[tl][ef * 16 + frow] = (f16)(acc[tf][ef][i] / den);
        }
    __syncthreads();
    for (int u = tid; u < 128 * 8; u += 256) {
        int tok = u >> 3, seg = u & 7;
        *(f16x8*)&attn[((size_t)(b * NTOK + t0 + tok)) * CC + h * DD + seg * 8] =
            *(const f16x8*)&qe[tok][seg * 8];
    }
}

// ---------------- fallback reg-staged proj ----------------
__device__ __forceinline__ void proj_epilogue(f32x4 (&acc)[4][4], int row0, int col0,
                                              const float* __restrict__ bias, float* __restrict__ out) {
    int lane = threadIdx.x & 63, wave = threadIdx.x >> 6;
    int wr = wave >> 1, wc = wave & 1;
    int rb = row0 + wr * 64 + 4 * (lane >> 4);
    int cb = col0 + wc * 64 + (lane & 15);
    #pragma unroll
    for (int n = 0; n < 4; ++n) {
        int j = cb + n * 16;
        float bj = bias[j];
        #pragma unroll
        for (int m = 0; m < 4; ++m)
            #pragma unroll
            for (int i = 0; i < 4; ++i) {
                int r = rb + m * 16 + i;
                if (r < BN_ROWS) out[(size_t)r * CC + j] = acc[m][n][i] + bj;
            }
    }
}

__global__ __launch_bounds__(256) void k_gemm_proj(const f16* __restrict__ A, const f16* __restrict__ Bm,
                                                   const float* __restrict__ bias, float* __restrict__ out) {
    __shared__ __attribute__((aligned(16))) f16 As[128][LDSK];
    __shared__ __attribute__((aligned(16))) f16 Bs[128][LDSK];
    f32x4 acc[4][4] = {};
    int row0 = blockIdx.x * 128, col0 = blockIdx.y * 128;
    gemm128_core<true>(A, Bm, CC, row0, col0, BN_ROWS, acc, As, Bs);
    proj_epilogue(acc, row0, col0, bias, out);
}

// ---------------- host ----------------
extern "C" void kernel_launch(void* const* d_in, const int* in_sizes, int n_in,
                              void* d_out, int out_size, void* d_ws, size_t ws_size,
                              hipStream_t stream) {
    const float* x = (const float*)d_in[0];
    const float* w_qkv = (const float*)d_in[1];
    const float* w_proj = (const float*)d_in[2];
    const float* b_proj = (const float*)d_in[3];
    const float* c_row = (const float*)d_in[4];
    const float* c_col = (const float*)d_in[5];
    const float* proj_feat = (const float*)d_in[6];
    float* out = (float*)d_out;
    char* ws = (char*)d_ws;
    char* ob = (char*)d_out;

    // ws layout
    const size_t O_WQKV  = 0;                        // 2304*768*2   = 3,538,944
    const size_t O_WPROJ = 3538944;                  // 768*768*2    = 1,179,648
    const size_t O_Q16   = 4718592;                  // 393600*64*2  = 50,380,800
    const size_t O_K16   = 55099392;                 // 50,380,800 (also attn alias)
    const size_t O_XW    = 105480192;                // 32896*768*2  = 50,528,256 (optional)
    const size_t NEED_B  = 105480192;
    const size_t NEED_A  = 156008448;
    if (ws_size < NEED_B) {
        k_diag<<<1, 64, 0, stream>>>(out, (float)((double)ws_size / 1048576.0));
        return;
    }
    const bool useA = (ws_size >= NEED_A);

    // d_out scratch layout (all dead before the final proj writes out)
    const size_t OD_V    = 0;                        // 384*64*1056*2 = 51,904,512
    const size_t OD_CTX  = 51904512;                 // 384*80*256*2  = 15,728,640
    const size_t OD_WC   = 67633152;                 // 3,145,728
    const size_t OD_NSQQ = 70778880;                 // 1,574,400
    const size_t OD_NSQK = 72353280;                 // 1,574,400
    const size_t OD_PF   = 73927680;                 // 32,768
    const size_t OD_AB   = 73960448;                 // 6,144

    f16* wqkv16  = (f16*)(ws + O_WQKV);
    f16* wproj16 = (f16*)(ws + O_WPROJ);
    f16* q16     = (f16*)(ws + O_Q16);
    f16* k16     = (f16*)(ws + O_K16);
    f16* xw16    = (f16*)(ws + O_XW);
    f16* v16t    = (f16*)(ob + OD_V);
    f16* ctxT    = (f16*)(ob + OD_CTX);
    float* wcirc = (float*)(ob + OD_WC);
    float* nsqq  = (float*)(ob + OD_NSQQ);
    float* nsqk  = (float*)(ob + OD_NSQK);
    f16* pfeat16 = (f16*)(ob + OD_PF);
    float* ab    = (float*)(ob + OD_AB);
    f16* attn16  = k16;   // k16 dead after k_fctx

    // conversions & precompute (merged, incl. ab)
    k_prep<<<9292, 256, 0, stream>>>(w_qkv, w_proj, proj_feat, c_row, c_col,
                                     wqkv16, wproj16, pfeat16, ab);
    k_wcirc<<<3072, 256, 0, stream>>>(ab, wcirc);

    // qkv GEMM + scatter
    if (useA) {
        k_cvt_x<<<24672, 256, 0, stream>>>(x, xw16);
        k_gemm_qkv_256<<<1161, 512, 0, stream>>>(xw16, wqkv16, q16, k16, v16t);
    } else {
        k_gemm_qkv_f32<<<dim3(257, 18), 256, 0, stream>>>(x, wqkv16, q16, k16, v16t);
    }
    // zero v16t pad columns + CLS norm_sq (merged)
    k_post<<<576, 256, 0, stream>>>(v16t, q16, k16, nsqq, nsqk);

    // STRING rotation (in-place)
    k_rotate<<<dim3(1024, 12), 256, 0, stream>>>(wcirc, q16, k16, nsqq, nsqk);

    // fused pipelines (fctx m-split x2 for CU balance)
    k_fctx<<<dim3(384, 2), 256, 0, stream>>>(k16, v16t, pfeat16, nsqk, ctxT);
    k_fnum<<<dim3(9, 384), 256, 0, stream>>>(q16, pfeat16, nsqq, ctxT, attn16);

    // output projection (overwrites all d_out scratch)
    if (useA) {
        k_gemm_proj_256<<<387, 512, 0, stream>>>(attn16, wproj16, b_proj, out);
    } else {
        k_gemm_proj<<<dim3(257, 6), 256, 0, stream>>>(attn16, wproj16, b_proj, out);
    }

    (void)in_sizes; (void)n_in; (void)out_size;
}